// Round 1
// baseline (1558.449 us; speedup 1.0000x reference)
//
#include <hip/hip_runtime.h>
#include <hip/hip_bf16.h>
#include <hip/hip_fp16.h>

#define NP 8192
#define DF 256
#define NROUNDS 13

typedef unsigned long long u64;

// ---------- helpers ----------

__device__ __forceinline__ u64 packKey(float v, int i, int j) {
  v = fmaxf(v, 0.0f);
  unsigned vb = __float_as_uint(v);      // nonneg float bits are order-preserving
  int a = i < j ? i : j;
  int b = i < j ? j : i;
  return ((u64)vb << 26) | ((u64)a << 13) | (u64)b;  // [57:26]=val [25:13]=min [12:0]=max
}

union F4H8 { float4 f; _Float16 h[8]; };

__device__ __forceinline__ void load8(const float* p, float* v) {
  float4 a = ((const float4*)p)[0], b = ((const float4*)p)[1];
  v[0]=a.x; v[1]=a.y; v[2]=a.z; v[3]=a.w; v[4]=b.x; v[5]=b.y; v[6]=b.z; v[7]=b.w;
}
__device__ __forceinline__ void load8(const _Float16* p, float* v) {
  F4H8 u; u.f = *(const float4*)p;
#pragma unroll
  for (int k = 0; k < 8; ++k) v[k] = (float)u.h[k];
}
__device__ __forceinline__ void store8(float* p, const float* v) {
  ((float4*)p)[0] = make_float4(v[0], v[1], v[2], v[3]);
  ((float4*)p)[1] = make_float4(v[4], v[5], v[6], v[7]);
}
__device__ __forceinline__ void store8(_Float16* p, const float* v) {
  F4H8 u;
#pragma unroll
  for (int k = 0; k < 8; ++k) u.h[k] = (_Float16)v[k];
  *(float4*)p = u.f;
}

// ---------- init ----------

__global__ void init_kernel(int* comp, int* edgeCnt) {
  int i = blockIdx.x * 256 + threadIdx.x;
  if (i < NP) comp[i] = i;
  if (i == 0) *edgeCnt = 0;
}

// ---------- row squared norms ----------

__global__ __launch_bounds__(64) void sq_kernel(const float* __restrict__ X, float* __restrict__ sq) {
  int i = blockIdx.x;
  float4 v = ((const float4*)(X + (size_t)i * DF))[threadIdx.x];
  float s = v.x * v.x + v.y * v.y + v.z * v.z + v.w * v.w;
#pragma unroll
  for (int off = 32; off >= 1; off >>= 1) s += __shfl_down(s, off);
  if (threadIdx.x == 0) sq[i] = s;
}

// ---------- d2 matrix build: 128x128 fp32 reg-tiled GEMM, fused epilogue ----------

template <typename T>
__global__ __launch_bounds__(256) void build_dist_kernel(
    const float* __restrict__ X, const float* __restrict__ sq, T* __restrict__ d2) {
  __shared__ float As[16][132];
  __shared__ float Bs[16][132];
  const int bi = blockIdx.y, bj = blockIdx.x;
  const int t = threadIdx.x;
  const int tx = t & 15, ty = t >> 4;
  const int m0 = bi * 128, n0 = bj * 128;
  float acc[8][8];
#pragma unroll
  for (int r = 0; r < 8; ++r)
#pragma unroll
    for (int c = 0; c < 8; ++c) acc[r][c] = 0.f;

  const int row = t >> 1;
  const int ks = (t & 1) * 8;
  for (int k0 = 0; k0 < DF; k0 += 16) {
    const float4* pa = (const float4*)(X + (size_t)(m0 + row) * DF + k0 + ks);
    float4 a0 = pa[0], a1 = pa[1];
    const float4* pb = (const float4*)(X + (size_t)(n0 + row) * DF + k0 + ks);
    float4 b0 = pb[0], b1 = pb[1];
    __syncthreads();
    As[ks + 0][row] = a0.x; As[ks + 1][row] = a0.y; As[ks + 2][row] = a0.z; As[ks + 3][row] = a0.w;
    As[ks + 4][row] = a1.x; As[ks + 5][row] = a1.y; As[ks + 6][row] = a1.z; As[ks + 7][row] = a1.w;
    Bs[ks + 0][row] = b0.x; Bs[ks + 1][row] = b0.y; Bs[ks + 2][row] = b0.z; Bs[ks + 3][row] = b0.w;
    Bs[ks + 4][row] = b1.x; Bs[ks + 5][row] = b1.y; Bs[ks + 6][row] = b1.z; Bs[ks + 7][row] = b1.w;
    __syncthreads();
#pragma unroll
    for (int kk = 0; kk < 16; ++kk) {
      float a[8], b[8];
#pragma unroll
      for (int r = 0; r < 8; ++r) a[r] = As[kk][ty * 8 + r];
#pragma unroll
      for (int c = 0; c < 8; ++c) b[c] = Bs[kk][tx * 8 + c];
#pragma unroll
      for (int r = 0; r < 8; ++r)
#pragma unroll
        for (int c = 0; c < 8; ++c) acc[r][c] = fmaf(a[r], b[c], acc[r][c]);
    }
  }
#pragma unroll
  for (int r = 0; r < 8; ++r) {
    int i = m0 + ty * 8 + r;
    float sqi = sq[i];
    float v[8];
#pragma unroll
    for (int c = 0; c < 8; ++c) {
      int j = n0 + tx * 8 + c;
      float dd = sqi + sq[j] - 2.f * acc[r][c];
      if (i == j) dd = INFINITY;
      v[c] = dd;
    }
    store8(d2 + (size_t)i * NP + n0 + tx * 8, v);
  }
}

// ---------- per-vertex min outgoing edge (also re-inits compmin for this round) ----------

template <typename T>
__global__ __launch_bounds__(256) void row_min_kernel(
    const T* __restrict__ d2, const int* __restrict__ comp,
    u64* __restrict__ rowbest, u64* __restrict__ compmin) {
  const int i = blockIdx.x;
  if (threadIdx.x == 0) compmin[i] = ~0ull;  // safe: compmin not read in this kernel
  const int ci = comp[i];
  const T* row = d2 + (size_t)i * NP;
  u64 best = ~0ull;
  for (int base = threadIdx.x * 8; base < NP; base += 256 * 8) {
    float v[8];
    load8(row + base, v);
    int4 c0 = *(const int4*)(comp + base);
    int4 c1 = *(const int4*)(comp + base + 4);
    int cs[8] = {c0.x, c0.y, c0.z, c0.w, c1.x, c1.y, c1.z, c1.w};
#pragma unroll
    for (int q = 0; q < 8; ++q) {
      if (cs[q] != ci) {
        u64 k = packKey(v[q], i, base + q);
        best = best < k ? best : k;
      }
    }
  }
#pragma unroll
  for (int off = 32; off >= 1; off >>= 1) {
    u64 o = __shfl_down(best, off);
    best = best < o ? best : o;
  }
  __shared__ u64 sred[4];
  const int lane = threadIdx.x & 63, wv = threadIdx.x >> 6;
  if (lane == 0) sred[wv] = best;
  __syncthreads();
  if (threadIdx.x == 0) {
    best = sred[0];
#pragma unroll
    for (int w = 1; w < 4; ++w) best = best < sred[w] ? best : sred[w];
    rowbest[i] = best;
  }
}

// ---------- per-component min via atomicMin on packed key ----------

__global__ void comp_atomic_kernel(const int* __restrict__ comp,
                                   const u64* __restrict__ rowbest,
                                   u64* __restrict__ compmin) {
  int i = blockIdx.x * blockDim.x + threadIdx.x;
  if (i >= NP) return;
  u64 b = rowbest[i];
  if (b != ~0ull) atomicMin(&compmin[comp[i]], b);
}

// ---------- select MST edges, dedupe mutual pairs, set parents ----------

template <typename T>
__global__ void select_kernel(const float* __restrict__ X, const float* __restrict__ sq,
                              const int* __restrict__ comp, const u64* __restrict__ compmin,
                              int* __restrict__ parent, float* __restrict__ edgeW,
                              int* __restrict__ edgeCnt) {
  int c = blockIdx.x * blockDim.x + threadIdx.x;
  if (c >= NP) return;
  u64 m = compmin[c];
  if (m == ~0ull) { parent[c] = c; return; }  // inactive id or finished
  int a = (int)((m >> 13) & 0x1FFF);
  int b = (int)(m & 0x1FFF);
  int i = (comp[a] == c) ? a : b;
  int j = (i == a) ? b : a;
  int d = comp[j];
  bool mutual = (compmin[d] == m);  // same edge is min for both components
  if (mutual && c > d) { parent[c] = d; return; }  // other side records the edge
  parent[c] = mutual ? c : d;                      // mutual smaller index becomes root
  float w;
  if constexpr (sizeof(T) == 4) {
    float dd = __uint_as_float((unsigned)(m >> 26));
    w = sqrtf(fmaxf(dd, 0.f) + 1e-12f);
  } else {
    // exact fp32 recompute of the selected edge weight
    const float4* pa = (const float4*)(X + (size_t)a * DF);
    const float4* pb = (const float4*)(X + (size_t)b * DF);
    float dot = 0.f;
#pragma unroll 8
    for (int k = 0; k < DF / 4; ++k) {
      float4 va = pa[k], vb = pb[k];
      dot += va.x * vb.x + va.y * vb.y + va.z * vb.z + va.w * vb.w;
    }
    float dd = sq[a] + sq[b] - 2.f * dot;
    w = sqrtf(fmaxf(dd, 0.f) + 1e-12f);
  }
  int idx = atomicAdd(edgeCnt, 1);
  if (idx < NP) edgeW[idx] = w;
}

// ---------- pointer-jump to roots + relabel (single block) ----------

__global__ __launch_bounds__(1024) void jump_relabel_kernel(int* __restrict__ parent,
                                                            int* __restrict__ comp) {
  for (int it = 0; it < 13; ++it) {
    for (int c = threadIdx.x; c < NP; c += 1024) parent[c] = parent[parent[c]];
    __syncthreads();
  }
  for (int i = threadIdx.x; i < NP; i += 1024) comp[i] = parent[comp[i]];
}

// ---------- entropy over edge weights ----------

__global__ __launch_bounds__(1024) void entropy_kernel(const float* __restrict__ edgeW,
                                                       const int* __restrict__ edgeCnt,
                                                       float* __restrict__ out) {
  __shared__ float sred[16];
  __shared__ float stot;
  int ne = *edgeCnt;
  if (ne > NP) ne = NP;
  float s = 0.f;
  for (int k = threadIdx.x; k < ne; k += 1024) s += edgeW[k];
#pragma unroll
  for (int off = 32; off >= 1; off >>= 1) s += __shfl_down(s, off);
  int lane = threadIdx.x & 63, wv = threadIdx.x >> 6;
  if (lane == 0) sred[wv] = s;
  __syncthreads();
  if (threadIdx.x == 0) {
    float t = 0.f;
#pragma unroll
    for (int w = 0; w < 16; ++w) t += sred[w];
    stot = t;
  }
  __syncthreads();
  float total = stot;
  float acc = 0.f;
  for (int k = threadIdx.x; k < ne; k += 1024) {
    float p = edgeW[k] / (total + 1e-12f);
    acc += p * logf(p + 1e-12f);
  }
#pragma unroll
  for (int off = 32; off >= 1; off >>= 1) acc += __shfl_down(acc, off);
  if (lane == 0) sred[wv] = acc;
  __syncthreads();
  if (threadIdx.x == 0) {
    float t = 0.f;
#pragma unroll
    for (int w = 0; w < 16; ++w) t += sred[w];
    out[0] = t;  // loss = -entropy = sum p*log(p+eps); WEIGHT = 1
  }
}

// ---------- host-side driver ----------

template <typename T>
static void run_boruvka(const float* X, float* sq, T* d2, int* comp, u64* rowbest,
                        u64* compmin, int* parent, float* edgeW, int* edgeCnt,
                        hipStream_t stream) {
  dim3 g(NP / 128, NP / 128);
  build_dist_kernel<T><<<g, 256, 0, stream>>>(X, sq, d2);
  for (int r = 0; r < NROUNDS; ++r) {
    row_min_kernel<T><<<NP, 256, 0, stream>>>(d2, comp, rowbest, compmin);
    comp_atomic_kernel<<<NP / 256, 256, 0, stream>>>(comp, rowbest, compmin);
    select_kernel<T><<<NP / 256, 256, 0, stream>>>(X, sq, comp, compmin, parent, edgeW, edgeCnt);
    jump_relabel_kernel<<<1, 1024, 0, stream>>>(parent, comp);
  }
}

extern "C" void kernel_launch(void* const* d_in, const int* in_sizes, int n_in,
                              void* d_out, int out_size, void* d_ws, size_t ws_size,
                              hipStream_t stream) {
  const float* X = (const float*)d_in[0];
  float* out = (float*)d_out;
  char* ws = (char*)d_ws;

  const size_t nn = (size_t)NP * NP;
  const size_t extraBytes = (size_t)NP * (4 + 4 + 8 + 8 + 4 + 4) + 64 + 1024;
  const bool useF32 = ws_size >= ((nn * 4 + 255) & ~(size_t)255) + extraBytes;

  size_t d2Bytes = nn * (useF32 ? 4 : 2);
  char* p = ws + ((d2Bytes + 255) & ~(size_t)255);
  float* sq = (float*)p;      p += (size_t)NP * 4;
  int* comp = (int*)p;        p += (size_t)NP * 4;
  u64* rowbest = (u64*)p;     p += (size_t)NP * 8;
  u64* compmin = (u64*)p;     p += (size_t)NP * 8;
  int* parent = (int*)p;      p += (size_t)NP * 4;
  float* edgeW = (float*)p;   p += (size_t)NP * 4;
  int* edgeCnt = (int*)p;

  init_kernel<<<NP / 256, 256, 0, stream>>>(comp, edgeCnt);
  sq_kernel<<<NP, 64, 0, stream>>>(X, sq);

  if (useF32) {
    run_boruvka<float>(X, sq, (float*)ws, comp, rowbest, compmin, parent, edgeW, edgeCnt, stream);
  } else {
    run_boruvka<_Float16>(X, sq, (_Float16*)ws, comp, rowbest, compmin, parent, edgeW, edgeCnt, stream);
  }

  entropy_kernel<<<1, 1024, 0, stream>>>(edgeW, edgeCnt, out);
}

// Round 2
// 395.275 us; speedup vs baseline: 3.9427x; 3.9427x over previous
//
#include <hip/hip_runtime.h>
#include <hip/hip_bf16.h>
#include <hip/hip_fp16.h>

#define NP 8192
#define DF 256
#define NROUNDS 13

typedef unsigned long long u64;
typedef unsigned short u16;
using bf16x8 = __attribute__((ext_vector_type(8))) short;
using f32x4  = __attribute__((ext_vector_type(4))) float;
using u16x8  = __attribute__((ext_vector_type(8))) u16;

__device__ __forceinline__ u16 f2bf(float f) {
  __hip_bfloat16 h = __float2bfloat16(f);
  return __builtin_bit_cast(u16, h);
}

// ---------- init ----------

__global__ void init_kernel(int* comp, u64* compmin, int* edgeCnt, int* nComps) {
  int i = blockIdx.x * 256 + threadIdx.x;
  if (i < NP) { comp[i] = i; compmin[i] = ~0ull; }
  if (i == 0) { *edgeCnt = 0; *nComps = NP; }
}

// ---------- row squared norms (fp32 exact) ----------

__global__ __launch_bounds__(64) void sq_kernel(const float* __restrict__ X, float* __restrict__ sq) {
  int i = blockIdx.x;
  float4 v = ((const float4*)(X + (size_t)i * DF))[threadIdx.x];
  float s = v.x * v.x + v.y * v.y + v.z * v.z + v.w * v.w;
#pragma unroll
  for (int off = 32; off >= 1; off >>= 1) s += __shfl_down(s, off);
  if (threadIdx.x == 0) sq[i] = s;
}

// ---------- fp32 -> bf16 conversion of X ----------

__global__ __launch_bounds__(256) void cvt_kernel(const float* __restrict__ X, u16* __restrict__ Xb) {
  int idx = (blockIdx.x * 256 + threadIdx.x) * 8;
  float4 a = ((const float4*)(X + idx))[0];
  float4 b = ((const float4*)(X + idx))[1];
  u16x8 o;
  o[0] = f2bf(a.x); o[1] = f2bf(a.y); o[2] = f2bf(a.z); o[3] = f2bf(a.w);
  o[4] = f2bf(b.x); o[5] = f2bf(b.y); o[6] = f2bf(b.z); o[7] = f2bf(b.w);
  *(u16x8*)(Xb + idx) = o;
}

// ---------- d2 build: bf16 MFMA 128x128 tile, fp32 acc, fp16 store ----------
// 256 threads = 4 waves in 2x2; each wave computes 64x64 via 4x4 frags of 16x16x32.

template <bool PRE>
__global__ __launch_bounds__(256) void build_dist_kernel(
    const float* __restrict__ X, const u16* __restrict__ Xb,
    const float* __restrict__ sq, _Float16* __restrict__ d2) {
  __shared__ __align__(16) u16 At[128 * 40];  // row stride 40 u16 = 80 B (bank-spread)
  __shared__ __align__(16) u16 Bt[128 * 40];
  const int t = threadIdx.x;
  const int m0 = blockIdx.y * 128, n0 = blockIdx.x * 128;
  const int wid = t >> 6, lane = t & 63;
  const int wm = wid >> 1, wn = wid & 1;
  const int lrow = lane & 15, lk = lane >> 4;
  f32x4 acc[4][4] = {};

  const int srow = t >> 1, shalf = t & 1;  // staging: 128 rows x 2 halves of 16 elems
  for (int k0 = 0; k0 < DF; k0 += 32) {
    u16x8 av0, av1, bv0, bv1;
    if (PRE) {
      const u16* pa = Xb + (size_t)(m0 + srow) * DF + k0 + shalf * 16;
      av0 = *(const u16x8*)pa; av1 = *(const u16x8*)(pa + 8);
      const u16* pb = Xb + (size_t)(n0 + srow) * DF + k0 + shalf * 16;
      bv0 = *(const u16x8*)pb; bv1 = *(const u16x8*)(pb + 8);
    } else {
      const float4* pa = (const float4*)(X + (size_t)(m0 + srow) * DF + k0 + shalf * 16);
      float4 a0 = pa[0], a1 = pa[1], a2 = pa[2], a3 = pa[3];
      av0[0]=f2bf(a0.x); av0[1]=f2bf(a0.y); av0[2]=f2bf(a0.z); av0[3]=f2bf(a0.w);
      av0[4]=f2bf(a1.x); av0[5]=f2bf(a1.y); av0[6]=f2bf(a1.z); av0[7]=f2bf(a1.w);
      av1[0]=f2bf(a2.x); av1[1]=f2bf(a2.y); av1[2]=f2bf(a2.z); av1[3]=f2bf(a2.w);
      av1[4]=f2bf(a3.x); av1[5]=f2bf(a3.y); av1[6]=f2bf(a3.z); av1[7]=f2bf(a3.w);
      const float4* pb = (const float4*)(X + (size_t)(n0 + srow) * DF + k0 + shalf * 16);
      float4 b0 = pb[0], b1 = pb[1], b2 = pb[2], b3 = pb[3];
      bv0[0]=f2bf(b0.x); bv0[1]=f2bf(b0.y); bv0[2]=f2bf(b0.z); bv0[3]=f2bf(b0.w);
      bv0[4]=f2bf(b1.x); bv0[5]=f2bf(b1.y); bv0[6]=f2bf(b1.z); bv0[7]=f2bf(b1.w);
      bv1[0]=f2bf(b2.x); bv1[1]=f2bf(b2.y); bv1[2]=f2bf(b2.z); bv1[3]=f2bf(b2.w);
      bv1[4]=f2bf(b3.x); bv1[5]=f2bf(b3.y); bv1[6]=f2bf(b3.z); bv1[7]=f2bf(b3.w);
    }
    __syncthreads();
    *(u16x8*)&At[srow * 40 + shalf * 16] = av0;
    *(u16x8*)&At[srow * 40 + shalf * 16 + 8] = av1;
    *(u16x8*)&Bt[srow * 40 + shalf * 16] = bv0;
    *(u16x8*)&Bt[srow * 40 + shalf * 16 + 8] = bv1;
    __syncthreads();
    bf16x8 af[4], bfr[4];
#pragma unroll
    for (int fm = 0; fm < 4; ++fm)
      af[fm] = *(const bf16x8*)&At[(wm * 64 + fm * 16 + lrow) * 40 + lk * 8];
#pragma unroll
    for (int fn = 0; fn < 4; ++fn)
      bfr[fn] = *(const bf16x8*)&Bt[(wn * 64 + fn * 16 + lrow) * 40 + lk * 8];
#pragma unroll
    for (int fm = 0; fm < 4; ++fm)
#pragma unroll
      for (int fn = 0; fn < 4; ++fn)
        acc[fm][fn] = __builtin_amdgcn_mfma_f32_16x16x32_bf16(af[fm], bfr[fn], acc[fm][fn], 0, 0, 0);
  }

  float sqj[4];
#pragma unroll
  for (int fn = 0; fn < 4; ++fn) sqj[fn] = sq[n0 + wn * 64 + fn * 16 + lrow];
#pragma unroll
  for (int fm = 0; fm < 4; ++fm) {
#pragma unroll
    for (int r = 0; r < 4; ++r) {
      int i = m0 + wm * 64 + fm * 16 + lk * 4 + r;  // C/D: col=lane&15, row=(lane>>4)*4+reg
      float si = sq[i];
#pragma unroll
      for (int fn = 0; fn < 4; ++fn) {
        int j = n0 + wn * 64 + fn * 16 + lrow;
        float dd = si + sqj[fn] - 2.0f * acc[fm][fn][r];
        dd = fmaxf(dd, 0.0f);
        if (i == j) dd = INFINITY;
        d2[(size_t)i * NP + j] = (_Float16)dd;
      }
    }
  }
}

// ---------- per-vertex min outgoing edge, block-level atomicMin into compmin ----------

__global__ __launch_bounds__(256) void row_min_kernel(
    const _Float16* __restrict__ d2, const int* __restrict__ comp,
    u64* __restrict__ compmin, const int* __restrict__ nComps) {
  if (*nComps == 1) return;
  const int i = blockIdx.x;
  const int ci = comp[i];
  const u16* row = (const u16*)(d2 + (size_t)i * NP);
  u64 best = ~0ull;
  for (int base = threadIdx.x * 8; base < NP; base += 256 * 8) {
    u16x8 v = *(const u16x8*)(row + base);
    int4 c0 = *(const int4*)(comp + base);
    int4 c1 = *(const int4*)(comp + base + 4);
    int cs[8] = {c0.x, c0.y, c0.z, c0.w, c1.x, c1.y, c1.z, c1.w};
#pragma unroll
    for (int q = 0; q < 8; ++q) {
      if (cs[q] != ci) {
        int j = base + q;
        int lo = i < j ? i : j;
        int hi = i ^ j ^ lo;
        u64 k = ((u64)v[q] << 26) | ((u64)lo << 13) | (u64)hi;
        best = k < best ? k : best;
      }
    }
  }
#pragma unroll
  for (int off = 32; off >= 1; off >>= 1) {
    u64 o = __shfl_down(best, off);
    best = best < o ? best : o;
  }
  __shared__ u64 sred[4];
  const int lane = threadIdx.x & 63, wv = threadIdx.x >> 6;
  if (lane == 0) sred[wv] = best;
  __syncthreads();
  if (threadIdx.x == 0) {
    best = sred[0];
#pragma unroll
    for (int w = 1; w < 4; ++w) best = best < sred[w] ? best : sred[w];
    if (best != ~0ull) atomicMin(&compmin[ci], best);
  }
}

// ---------- select MST edges (structural 2-cycle dedupe), exact fp32 weights ----------

__global__ void select_kernel(const float* __restrict__ X, const float* __restrict__ sq,
                              const int* __restrict__ comp, const u64* __restrict__ compmin,
                              int* __restrict__ parent, float* __restrict__ edgeW,
                              int* __restrict__ edgeCnt, const int* __restrict__ nComps) {
  int c = blockIdx.x * blockDim.x + threadIdx.x;
  if (c >= NP) return;
  if (*nComps == 1) { parent[c] = c; return; }
  u64 m = compmin[c];
  if (m == ~0ull) { parent[c] = c; return; }
  int a = (int)((m >> 13) & 0x1FFF);
  int b = (int)(m & 0x1FFF);
  int j = (comp[a] == c) ? b : a;
  int d = comp[j];
  // structural mutual detection: does d's min edge point back at c?
  bool mutual = false;
  u64 md = compmin[d];
  if (md != ~0ull) {
    int a2 = (int)((md >> 13) & 0x1FFF);
    int b2 = (int)(md & 0x1FFF);
    int j2 = (comp[a2] == d) ? b2 : a2;
    mutual = (comp[j2] == c);
  }
  if (mutual && c > d) { parent[c] = d; return; }  // partner records the edge
  parent[c] = mutual ? c : d;
  // exact fp32 recompute of the selected edge weight
  const float4* pa = (const float4*)(X + (size_t)a * DF);
  const float4* pb = (const float4*)(X + (size_t)b * DF);
  float dot = 0.f;
#pragma unroll 8
  for (int k = 0; k < DF / 4; ++k) {
    float4 va = pa[k], vb = pb[k];
    dot += va.x * vb.x + va.y * vb.y + va.z * vb.z + va.w * vb.w;
  }
  float dd = sq[a] + sq[b] - 2.f * dot;
  float w = sqrtf(fmaxf(dd, 0.f) + 1e-12f);
  int idx = atomicAdd(edgeCnt, 1);
  if (idx < NP) edgeW[idx] = w;
}

// ---------- LDS pointer-jump + relabel + component count + compmin reset ----------

__global__ __launch_bounds__(1024) void jump_relabel_kernel(
    const int* __restrict__ parent, int* __restrict__ comp,
    u64* __restrict__ compmin, int* __restrict__ nComps) {
  if (*nComps == 1) return;
  __shared__ int sp[NP];
  __shared__ unsigned char fl[NP];
  __shared__ int scnt;
  const int t = threadIdx.x;
  for (int c = t; c < NP; c += 1024) { sp[c] = parent[c]; fl[c] = 0; }
  if (t == 0) scnt = 0;
  __syncthreads();
  for (int it = 0; it < 13; ++it) {
    for (int c = t; c < NP; c += 1024) sp[c] = sp[sp[c]];
    __syncthreads();
  }
  int part = 0;
  for (int i = t; i < NP; i += 1024) {
    int nc = sp[comp[i]];
    comp[i] = nc;
    fl[nc] = 1;
  }
  __syncthreads();
  for (int c = t; c < NP; c += 1024) part += fl[c];
#pragma unroll
  for (int off = 32; off >= 1; off >>= 1) part += __shfl_down(part, off);
  if ((t & 63) == 0) atomicAdd(&scnt, part);
  for (int c = t; c < NP; c += 1024) compmin[c] = ~0ull;
  __syncthreads();
  if (t == 0) *nComps = scnt;
}

// ---------- entropy over edge weights ----------

__global__ __launch_bounds__(1024) void entropy_kernel(const float* __restrict__ edgeW,
                                                       const int* __restrict__ edgeCnt,
                                                       float* __restrict__ out) {
  __shared__ float sred[16];
  __shared__ float stot;
  int ne = *edgeCnt;
  if (ne > NP) ne = NP;
  float s = 0.f;
  for (int k = threadIdx.x; k < ne; k += 1024) s += edgeW[k];
#pragma unroll
  for (int off = 32; off >= 1; off >>= 1) s += __shfl_down(s, off);
  int lane = threadIdx.x & 63, wv = threadIdx.x >> 6;
  if (lane == 0) sred[wv] = s;
  __syncthreads();
  if (threadIdx.x == 0) {
    float tt = 0.f;
#pragma unroll
    for (int w = 0; w < 16; ++w) tt += sred[w];
    stot = tt;
  }
  __syncthreads();
  float total = stot;
  float acc = 0.f;
  for (int k = threadIdx.x; k < ne; k += 1024) {
    float p = edgeW[k] / (total + 1e-12f);
    acc += p * logf(p + 1e-12f);
  }
#pragma unroll
  for (int off = 32; off >= 1; off >>= 1) acc += __shfl_down(acc, off);
  if (lane == 0) sred[wv] = acc;
  __syncthreads();
  if (threadIdx.x == 0) {
    float tt = 0.f;
#pragma unroll
    for (int w = 0; w < 16; ++w) tt += sred[w];
    out[0] = tt;  // loss = -entropy = sum p*log(p+eps); WEIGHT = 1
  }
}

// ---------- host-side driver ----------

extern "C" void kernel_launch(void* const* d_in, const int* in_sizes, int n_in,
                              void* d_out, int out_size, void* d_ws, size_t ws_size,
                              hipStream_t stream) {
  const float* X = (const float*)d_in[0];
  float* out = (float*)d_out;
  char* ws = (char*)d_ws;

  const size_t nn = (size_t)NP * NP;
  size_t off = (nn * 2 + 255) & ~(size_t)255;  // fp16 d2
  _Float16* d2 = (_Float16*)ws;
  float* sq = (float*)(ws + off);      off += (size_t)NP * 4;
  int* comp = (int*)(ws + off);        off += (size_t)NP * 4;
  u64* compmin = (u64*)(ws + off);     off += (size_t)NP * 8;
  int* parent = (int*)(ws + off);      off += (size_t)NP * 4;
  float* edgeW = (float*)(ws + off);   off += (size_t)NP * 4;
  int* edgeCnt = (int*)(ws + off);     off += 64;
  int* nComps = (int*)(ws + off);      off += 64;
  off = (off + 255) & ~(size_t)255;
  u16* Xb = (u16*)(ws + off);
  const bool PRE = (ws_size >= off + (size_t)NP * DF * 2);

  init_kernel<<<NP / 256, 256, 0, stream>>>(comp, compmin, edgeCnt, nComps);
  sq_kernel<<<NP, 64, 0, stream>>>(X, sq);
  if (PRE) {
    cvt_kernel<<<NP * DF / (256 * 8), 256, 0, stream>>>(X, Xb);
    build_dist_kernel<true><<<dim3(NP / 128, NP / 128), 256, 0, stream>>>(X, Xb, sq, d2);
  } else {
    build_dist_kernel<false><<<dim3(NP / 128, NP / 128), 256, 0, stream>>>(X, Xb, sq, d2);
  }
  for (int r = 0; r < NROUNDS; ++r) {
    row_min_kernel<<<NP, 256, 0, stream>>>(d2, comp, compmin, nComps);
    select_kernel<<<NP / 256, 256, 0, stream>>>(X, sq, comp, compmin, parent, edgeW, edgeCnt, nComps);
    jump_relabel_kernel<<<1, 1024, 0, stream>>>(parent, comp, compmin, nComps);
  }
  entropy_kernel<<<1, 1024, 0, stream>>>(edgeW, edgeCnt, out);
}